// Round 8
// baseline (118.860 us; speedup 1.0000x reference)
//
#include <hip/hip_runtime.h>

#define HH 80
#define WW 80
#define IMG (HH * WW)             // 6400
#define NV ((HH - 1) * WW)        // 6320 vertical edge slots
#define NPTS (NV + HH * (WW - 1)) // 12640 edge slots per image
#define NPIX (2 * IMG)            // 12800
#define BIGF 1.0e10f
#define INVC 1.0e7f
#define EPSF 1e-8f
#define QSCALE 131072.0f          // 2^17 fixed point (exact-commutative sums)

// k_prep geometry: each set padded to 12800 slots = 50 blocks x 256 threads
#define SETPAD 12800
#define SBLOCKS (SETPAD / 256)    // 50 blocks per set
#define EXBLOCKS (4 * SBLOCKS)    // 200 extraction blocks
#define PXBLOCKS (NPIX / 256)     // 50 pixel blocks
#define PREPB (EXBLOCKS + PXBLOCKS) // 250

// k_minfin geometry
#define BLK 256                   // 4 waves
#define APT 8                     // A points per thread
#define ACHUNK (BLK * APT)        // 2048
#define WORSTAB ((NPTS + ACHUNK - 1) / ACHUNK) // 7
#define NSLICE 32
#define MAXSLICE ((((NPTS + NSLICE - 1) / NSLICE) + 1) & ~1) // 396
#define MINB (WORSTAB * NSLICE * 4) // 896 blocks

// scalar ws layout (each contended counter on its own 128-B line)
#define CNT_STRIDE 32             // ints; cnt[set] at d_ws + set*128
#define PIX_OFF 512
#define TICKET_OFF 640
#define SCALAR_BYTES 1024

__device__ __forceinline__ long long wave_reduce_ll(long long v) {
#pragma unroll
  for (int o = 32; o > 0; o >>= 1) {
    int2 p = *(int2*)&v;
    p.x = __shfl_down(p.x, o, 64);
    p.y = __shfl_down(p.y, o, 64);
    v += *(long long*)&p;
  }
  return v;
}

// --------------------------------------------------------------- k_zero
// Zeroes the 1024-byte scalar area (cnt lines, pix_i, ticket).
__global__ void k_zero(unsigned int* __restrict__ w) {
  w[threadIdx.x] = 0u;   // 256 threads x 4 B = 1024 B
}

// --------------------------------------------------------------- k_prep
// 250 blocks. minarr init + (blocks 0..199) zero-crossing extraction with
// block-aggregated atomic append (one atomicAdd per block, counters on
// separate cache lines) + (blocks 200..249) pixel loss in exact int64.
// Append ORDER is non-deterministic, but all consumers are order-invariant
// and exact (multiset min; int64 sums) -> output bitwise stable.
__global__ void __launch_bounds__(256) k_prep(
    const float* __restrict__ pred, const float* __restrict__ gt,
    float2* __restrict__ pts, float* __restrict__ minarr,
    int* __restrict__ cnt, unsigned long long* __restrict__ pix_i) {
  __shared__ int wc[4], wo[4];
  __shared__ long long rl[4];
  int tid = threadIdx.x, lane = tid & 63, wid = tid >> 6;
  int gtid = blockIdx.x * 256 + tid;

  if (gtid < 4 * NPTS) minarr[gtid] = BIGF;

  if (blockIdx.x < EXBLOCKS) {
    int set = blockIdx.x / SBLOCKS;
    int idx = (blockIdx.x % SBLOCKS) * 256 + tid;   // slot in [0, SETPAD)
    const float* s = (set < 2 ? pred : gt) + (set & 1) * IMG;
    float r = 0.f, c = 0.f;
    bool valid = false;
    if (idx < NPTS) {
      if (idx < NV) {
        int i = idx / WW, j = idx - i * WW;
        float v1 = s[i * WW + j], v2 = s[(i + 1) * WW + j];
        c = (float)j;
        if (v1 == 0.f)      { r = (float)i;       valid = true; }
        else if (v2 == 0.f) { r = (float)i + 1.f; valid = true; }
        else {
          r = (float)i + fabsf(v1) / (fabsf(v1) + fabsf(v2) + EPSF);
          valid = (v1 * v2 < 0.f);
        }
      } else {
        int t = idx - NV;
        int i = t / (WW - 1), j = t - i * (WW - 1);
        float h1 = s[i * WW + j], h2 = s[i * WW + j + 1];
        r = (float)i;
        if (h1 == 0.f)      { c = (float)j;       valid = true; }
        else if (h2 == 0.f) { c = (float)j + 1.f; valid = true; }
        else {
          c = (float)j + fabsf(h1) / (fabsf(h1) + fabsf(h2) + EPSF);
          valid = (h1 * h2 < 0.f);
        }
      }
    }
    unsigned long long mask = __ballot(valid);
    int nw = __popcll(mask);
    if (lane == 0) wc[wid] = nw;
    __syncthreads();
    if (tid == 0) {
      int t0 = wc[0], t1 = wc[1], t2 = wc[2], t3 = wc[3];
      int tot = t0 + t1 + t2 + t3;
      int base = tot ? atomicAdd(&cnt[set * CNT_STRIDE], tot) : 0;
      wo[0] = base; wo[1] = base + t0; wo[2] = base + t0 + t1;
      wo[3] = base + t0 + t1 + t2;
    }
    __syncthreads();
    if (valid) {
      int lpos = __popcll(mask & ((1ull << lane) - 1ull));
      pts[set * NPTS + wo[wid] + lpos] = make_float2(r, c);
    }
  } else {
    int p = (blockIdx.x - EXBLOCKS) * 256 + tid;
    float d = fabsf(pred[p] - gt[p]);
    long long q = (long long)(d * QSCALE + 0.5f);
    q = wave_reduce_ll(q);
    if (lane == 0) rl[wid] = q;
    __syncthreads();
    if (tid == 0)
      atomicAdd(pix_i, (unsigned long long)(rl[0] + rl[1] + rl[2] + rl[3]));
  }
}

// --------------------------------------------------------------- k_minfin
// dir 0: A=0 B=2 | 1: A=2 B=0 | 2: A=1 B=3 | 3: A=3 B=1
// min over b of (q2 - 2px*qx - 2py*qy); +p2 and sqrt are monotone (sqrt in
// the lights-out tail). Last block (ticket) does exact int64 sums + writes out.
__global__ void __launch_bounds__(BLK) k_minfin(
    const float2* __restrict__ pts, float* __restrict__ minarr,
    const int* __restrict__ cnt, const unsigned long long* __restrict__ pix_i,
    unsigned int* __restrict__ ticket, float* __restrict__ out) {
  __shared__ float4 tile[MAXSLICE];
  __shared__ long long rl[4];
  __shared__ int fin_s;
  int tid = threadIdx.x, lane = tid & 63, wid = tid >> 6;

  int dir = blockIdx.z;
  int Aset = ((dir & 1) << 1) | (dir >> 1);
  int Bset = Aset ^ 2;
  int cntA = cnt[Aset * CNT_STRIDE], cntB = cnt[Bset * CNT_STRIDE];

  int abase0 = blockIdx.x * ACHUNK;
  int slicelen = (((cntB + NSLICE - 1) / NSLICE) + 1) & ~1;
  int b0 = blockIdx.y * slicelen;

  if (abase0 < cntA && b0 < cntB) {   // block-uniform condition
    int n = min(slicelen, cntB - b0);
    int sn = (n + 1) & ~1;            // pad to even with a dummy far point
    for (int i = tid; i < sn; i += BLK) {
      float2 q = (i < n) ? pts[Bset * NPTS + b0 + i] : make_float2(INVC, INVC);
      tile[i] = make_float4(q.x, q.y, fmaf(q.x, q.x, q.y * q.y), 0.f);
    }
    __syncthreads();

    int abase = abase0 + tid;
    float nx[APT], ny[APT], p2[APT], m[APT];
#pragma unroll
    for (int i = 0; i < APT; ++i) {
      int a = abase + i * BLK;
      float2 p = (a < cntA) ? pts[Aset * NPTS + a] : make_float2(0.f, 0.f);
      nx[i] = -2.f * p.x;
      ny[i] = -2.f * p.y;
      p2[i] = fmaf(p.x, p.x, p.y * p.y);
      m[i] = 3.0e38f;
    }

#pragma unroll 2
    for (int b = 0; b < sn; b += 2) {
      float4 q0 = tile[b];
      float4 q1 = tile[b + 1];
#pragma unroll
      for (int i = 0; i < APT; ++i) {
        float t0 = fmaf(ny[i], q0.y, fmaf(nx[i], q0.x, q0.z));
        float t1 = fmaf(ny[i], q1.y, fmaf(nx[i], q1.x, q1.z));
        m[i] = fminf(fminf(t0, t1), m[i]);   // -> v_min3_f32
      }
    }

#pragma unroll
    for (int i = 0; i < APT; ++i) {
      int a = abase + i * BLK;
      if (a < cntA) {
        float d2 = fmaxf(m[i] + p2[i], 0.f);
        // non-negative floats order as uint bit patterns; min is order-exact
        atomicMin((unsigned int*)&minarr[Aset * NPTS + a], __float_as_uint(d2));
      }
    }
  }

  // ---- ticket lights-out (every block, including early-exit ones)
  __syncthreads();
  __threadfence();
  if (tid == 0) {
    unsigned int t = __hip_atomic_fetch_add(ticket, 1u, __ATOMIC_ACQ_REL,
                                            __HIP_MEMORY_SCOPE_AGENT);
    fin_s = (t == MINB - 1) ? 1 : 0;
  }
  __syncthreads();
  if (!fin_s) return;

  // ---- last block: exact int64 sums of round(sqrt(d2)*2^17), then combine
  long long tot[4];
  for (int set = 0; set < 4; ++set) {
    int n = cnt[set * CNT_STRIDE];
    long long ls = 0;
    for (int i = tid; i < n; i += BLK) {
      float d2 = __hip_atomic_load(&minarr[set * NPTS + i], __ATOMIC_RELAXED,
                                   __HIP_MEMORY_SCOPE_AGENT);
      ls += (long long)(sqrtf(d2) * QSCALE + 0.5f);
    }
    ls = wave_reduce_ll(ls);
    if (lane == 0) rl[wid] = ls;
    __syncthreads();
    if (tid == 0) tot[set] = rl[0] + rl[1] + rl[2] + rl[3];
    __syncthreads();
  }
  if (tid == 0) {
    const float iq = 1.0f / QSCALE;
    float ss0 = (float)tot[0] * iq, ss1 = (float)tot[1] * iq;
    float ss2 = (float)tot[2] * iq, ss3 = (float)tot[3] * iq;
    float n0 = fmaxf((float)cnt[0 * CNT_STRIDE], 1.f);
    float n1 = fmaxf((float)cnt[1 * CNT_STRIDE], 1.f);
    float n2 = fmaxf((float)cnt[2 * CNT_STRIDE], 1.f);
    float n3 = fmaxf((float)cnt[3 * CNT_STRIDE], 1.f);
    float ch0 = -ss0 / n0 + ss2 / n2;
    float ch1 = -ss1 / n1 + ss3 / n3;
    unsigned long long pix = __hip_atomic_load(pix_i, __ATOMIC_RELAXED,
                                               __HIP_MEMORY_SCOPE_AGENT);
    out[0] = (float)(long long)pix * iq / (float)NPIX;
    out[1] = 0.5f * (ch0 + ch1);
  }
}

extern "C" void kernel_launch(void* const* d_in, const int* in_sizes, int n_in,
                              void* d_out, int out_size, void* d_ws, size_t ws_size,
                              hipStream_t stream) {
  const float* pred = (const float*)d_in[0];
  const float* gt   = (const float*)d_in[1];
  float* out = (float*)d_out;

  // ws: [0..1023] scalars (zeroed by k_zero) | 4*NPTS float2 pts | 4*NPTS float mins
  int* cnt = (int*)d_ws;                                                // lines @0,128,256,384
  unsigned long long* pix_i = (unsigned long long*)((char*)d_ws + PIX_OFF);
  unsigned int* ticket = (unsigned int*)((char*)d_ws + TICKET_OFF);
  float2* pts   = (float2*)((char*)d_ws + SCALAR_BYTES);
  float* minarr = (float*)((char*)d_ws + SCALAR_BYTES + sizeof(float2) * 4 * NPTS);

  k_zero<<<1, 256, 0, stream>>>((unsigned int*)d_ws);
  k_prep<<<PREPB, 256, 0, stream>>>(pred, gt, pts, minarr, cnt, pix_i);
  k_minfin<<<dim3(WORSTAB, NSLICE, 4), BLK, 0, stream>>>(pts, minarr, cnt, pix_i, ticket, out);
}

// Round 9
// 38.586 us; speedup vs baseline: 3.0804x; 3.0804x over previous
//
#include <hip/hip_runtime.h>

#define HH 80
#define WW 80
#define IMG (HH * WW)             // 6400
#define NV ((HH - 1) * WW)        // 6320 vertical edge slots
#define NPTS (NV + HH * (WW - 1)) // 12640 edge slots per image
#define NPIX (2 * IMG)            // 12800
#define BIGF 1.0e10f
#define INVC 1.0e7f
#define EPSF 1e-8f
#define QSCALE 131072.0f          // 2^17 fixed point (exact-commutative sums)

// k_prep geometry: each set padded to 12800 slots = 50 blocks x 256 threads
#define SETPAD 12800
#define SBLOCKS (SETPAD / 256)    // 50 blocks per set
#define EXBLOCKS (4 * SBLOCKS)    // 200 extraction blocks
#define PXBLOCKS (NPIX / 256)     // 50 pixel blocks
#define PREPB (EXBLOCKS + PXBLOCKS) // 250

// k_min geometry
#define BLK 256                   // 4 waves
#define APT 8                     // A points per thread
#define ACHUNK (BLK * APT)        // 2048
#define ABLOCKS ((NPTS + ACHUNK - 1) / ACHUNK) // 7 worst case; ~4 active
#define NSLICE 32
#define MAXSLICE ((((NPTS + NSLICE - 1) / NSLICE) + 1) & ~1) // 396

// scalar ws layout (each contended counter on its own 128-B line)
#define CNT_STRIDE 32             // ints; cnt[set] at d_ws + set*128
#define PIX_OFF 512
#define TICKET_OFF 640
#define SUM_OFF 768               // 4 x u64
#define SCALAR_BYTES 1024

__device__ __forceinline__ long long wave_reduce_ll(long long v) {
#pragma unroll
  for (int o = 32; o > 0; o >>= 1) {
    int2 p = *(int2*)&v;
    p.x = __shfl_down(p.x, o, 64);
    p.y = __shfl_down(p.y, o, 64);
    v += *(long long*)&p;
  }
  return v;
}

// --------------------------------------------------------------- k_zero
__global__ void k_zero(unsigned int* __restrict__ w) {
  w[threadIdx.x] = 0u;   // 256 threads x 4 B = 1024 B
}

// --------------------------------------------------------------- k_prep
// 250 blocks. minarr init + (blocks 0..199) zero-crossing extraction with
// block-aggregated atomic append (one atomicAdd per block, counters on
// separate cache lines) + (blocks 200..249) pixel loss in exact int64.
// Append ORDER is non-deterministic, but all consumers are order-invariant
// and exact (multiset min; int64 sums) -> output bitwise stable.
__global__ void __launch_bounds__(256) k_prep(
    const float* __restrict__ pred, const float* __restrict__ gt,
    float2* __restrict__ pts, float* __restrict__ minarr,
    int* __restrict__ cnt, unsigned long long* __restrict__ pix_i) {
  __shared__ int wc[4], wo[4];
  __shared__ long long rl[4];
  int tid = threadIdx.x, lane = tid & 63, wid = tid >> 6;
  int gtid = blockIdx.x * 256 + tid;

  if (gtid < 4 * NPTS) minarr[gtid] = BIGF;

  if (blockIdx.x < EXBLOCKS) {
    int set = blockIdx.x / SBLOCKS;
    int idx = (blockIdx.x % SBLOCKS) * 256 + tid;   // slot in [0, SETPAD)
    const float* s = (set < 2 ? pred : gt) + (set & 1) * IMG;
    float r = 0.f, c = 0.f;
    bool valid = false;
    if (idx < NPTS) {
      if (idx < NV) {
        int i = idx / WW, j = idx - i * WW;
        float v1 = s[i * WW + j], v2 = s[(i + 1) * WW + j];
        c = (float)j;
        if (v1 == 0.f)      { r = (float)i;       valid = true; }
        else if (v2 == 0.f) { r = (float)i + 1.f; valid = true; }
        else {
          r = (float)i + fabsf(v1) / (fabsf(v1) + fabsf(v2) + EPSF);
          valid = (v1 * v2 < 0.f);
        }
      } else {
        int t = idx - NV;
        int i = t / (WW - 1), j = t - i * (WW - 1);
        float h1 = s[i * WW + j], h2 = s[i * WW + j + 1];
        r = (float)i;
        if (h1 == 0.f)      { c = (float)j;       valid = true; }
        else if (h2 == 0.f) { c = (float)j + 1.f; valid = true; }
        else {
          c = (float)j + fabsf(h1) / (fabsf(h1) + fabsf(h2) + EPSF);
          valid = (h1 * h2 < 0.f);
        }
      }
    }
    unsigned long long mask = __ballot(valid);
    int nw = __popcll(mask);
    if (lane == 0) wc[wid] = nw;
    __syncthreads();
    if (tid == 0) {
      int t0 = wc[0], t1 = wc[1], t2 = wc[2], t3 = wc[3];
      int tot = t0 + t1 + t2 + t3;
      int base = tot ? atomicAdd(&cnt[set * CNT_STRIDE], tot) : 0;
      wo[0] = base; wo[1] = base + t0; wo[2] = base + t0 + t1;
      wo[3] = base + t0 + t1 + t2;
    }
    __syncthreads();
    if (valid) {
      int lpos = __popcll(mask & ((1ull << lane) - 1ull));
      pts[set * NPTS + wo[wid] + lpos] = make_float2(r, c);
    }
  } else {
    int p = (blockIdx.x - EXBLOCKS) * 256 + tid;
    float d = fabsf(pred[p] - gt[p]);
    long long q = (long long)(d * QSCALE + 0.5f);
    q = wave_reduce_ll(q);
    if (lane == 0) rl[wid] = q;
    __syncthreads();
    if (tid == 0)
      atomicAdd(pix_i, (unsigned long long)(rl[0] + rl[1] + rl[2] + rl[3]));
  }
}

// --------------------------------------------------------------- k_min
// dir 0: A=0 B=2 | 1: A=2 B=0 | 2: A=1 B=3 | 3: A=3 B=1
// min over b of (q2 - 2px*qx - 2py*qy); +p2 and sqrt are monotone (sqrt in k_fin).
// NO device-scope fence here: per-block device fences at O(1000) blocks cost
// ~100 us on 8-XCD MI355X (measured r5/r8) — final reduce lives in k_fin.
__global__ void __launch_bounds__(BLK) k_min(
    const float2* __restrict__ pts, float* __restrict__ minarr,
    const int* __restrict__ cnt) {
  int dir = blockIdx.z;
  int Aset = ((dir & 1) << 1) | (dir >> 1);
  int Bset = Aset ^ 2;
  int cntA = cnt[Aset * CNT_STRIDE], cntB = cnt[Bset * CNT_STRIDE];

  int abase0 = blockIdx.x * ACHUNK;
  if (abase0 >= cntA) return;
  int slicelen = (((cntB + NSLICE - 1) / NSLICE) + 1) & ~1;
  int b0 = blockIdx.y * slicelen;
  if (b0 >= cntB) return;
  int n = min(slicelen, cntB - b0);
  int sn = (n + 1) & ~1;  // pad to even with a dummy far point

  __shared__ float4 tile[MAXSLICE];
  for (int i = threadIdx.x; i < sn; i += BLK) {
    float2 q = (i < n) ? pts[Bset * NPTS + b0 + i] : make_float2(INVC, INVC);
    tile[i] = make_float4(q.x, q.y, fmaf(q.x, q.x, q.y * q.y), 0.f);
  }
  __syncthreads();

  int abase = abase0 + threadIdx.x;
  float nx[APT], ny[APT], p2[APT], m[APT];
#pragma unroll
  for (int i = 0; i < APT; ++i) {
    int a = abase + i * BLK;
    float2 p = (a < cntA) ? pts[Aset * NPTS + a] : make_float2(0.f, 0.f);
    nx[i] = -2.f * p.x;
    ny[i] = -2.f * p.y;
    p2[i] = fmaf(p.x, p.x, p.y * p.y);
    m[i] = 3.0e38f;
  }

#pragma unroll 2
  for (int b = 0; b < sn; b += 2) {
    float4 q0 = tile[b];
    float4 q1 = tile[b + 1];
#pragma unroll
    for (int i = 0; i < APT; ++i) {
      float t0 = fmaf(ny[i], q0.y, fmaf(nx[i], q0.x, q0.z));
      float t1 = fmaf(ny[i], q1.y, fmaf(nx[i], q1.x, q1.z));
      m[i] = fminf(fminf(t0, t1), m[i]);   // -> v_min3_f32
    }
  }

#pragma unroll
  for (int i = 0; i < APT; ++i) {
    int a = abase + i * BLK;
    if (a < cntA) {
      float d2 = fmaxf(m[i] + p2[i], 0.f);
      // non-negative floats order as uint bit patterns; min is order-exact
      atomicMin((unsigned int*)&minarr[Aset * NPTS + a], __float_as_uint(d2));
    }
  }
}

// --------------------------------------------------------------- k_fin
// 16 blocks (4 per set): exact int64 partial sums of round(sqrt(d2)*2^17),
// device-scope atomicAdd (order-independent, bit-exact). Ticketed last block
// combines and writes the two outputs. 16 device fences total = cheap.
__global__ void __launch_bounds__(256) k_fin(
    const float* __restrict__ minarr, const int* __restrict__ cnt,
    const unsigned long long* __restrict__ pix_i,
    unsigned long long* __restrict__ sum_i,
    unsigned int* __restrict__ ticket, float* __restrict__ out) {
  int set = blockIdx.x >> 2, q = blockIdx.x & 3;
  int tid = threadIdx.x, lane = tid & 63;
  int n = cnt[set * CNT_STRIDE];

  long long ls = 0;
  for (int i = q * 256 + tid; i < n; i += 1024) {
    float d = sqrtf(minarr[set * NPTS + i]);
    ls += (long long)(d * QSCALE + 0.5f);
  }
  ls = wave_reduce_ll(ls);
  if (lane == 0) atomicAdd(&sum_i[set], (unsigned long long)ls);
  __syncthreads();

  if (tid == 0) {
    __threadfence();
    unsigned int t = atomicAdd(ticket, 1u);
    if (t == 15u) {  // all 16 blocks' adds complete (device-scope atomics)
      const float iq = 1.0f / QSCALE;
      float ss[4];
      for (int k = 0; k < 4; ++k)
        ss[k] = (float)((long long)atomicAdd(&sum_i[k], 0ull)) * iq;
      float n0 = fmaxf((float)cnt[0 * CNT_STRIDE], 1.f);
      float n1 = fmaxf((float)cnt[1 * CNT_STRIDE], 1.f);
      float n2 = fmaxf((float)cnt[2 * CNT_STRIDE], 1.f);
      float n3 = fmaxf((float)cnt[3 * CNT_STRIDE], 1.f);
      float ch0 = -ss[0] / n0 + ss[2] / n2;
      float ch1 = -ss[1] / n1 + ss[3] / n3;
      out[0] = (float)(long long)(*pix_i) * iq / (float)NPIX;
      out[1] = 0.5f * (ch0 + ch1);
    }
  }
}

extern "C" void kernel_launch(void* const* d_in, const int* in_sizes, int n_in,
                              void* d_out, int out_size, void* d_ws, size_t ws_size,
                              hipStream_t stream) {
  const float* pred = (const float*)d_in[0];
  const float* gt   = (const float*)d_in[1];
  float* out = (float*)d_out;

  // ws: [0..1023] scalars (zeroed by k_zero) | 4*NPTS float2 pts | 4*NPTS float mins
  int* cnt = (int*)d_ws;                                                // lines @0,128,256,384
  unsigned long long* pix_i = (unsigned long long*)((char*)d_ws + PIX_OFF);
  unsigned int* ticket = (unsigned int*)((char*)d_ws + TICKET_OFF);
  unsigned long long* sum_i = (unsigned long long*)((char*)d_ws + SUM_OFF);
  float2* pts   = (float2*)((char*)d_ws + SCALAR_BYTES);
  float* minarr = (float*)((char*)d_ws + SCALAR_BYTES + sizeof(float2) * 4 * NPTS);

  k_zero<<<1, 256, 0, stream>>>((unsigned int*)d_ws);
  k_prep<<<PREPB, 256, 0, stream>>>(pred, gt, pts, minarr, cnt, pix_i);
  k_min<<<dim3(ABLOCKS, NSLICE, 4), BLK, 0, stream>>>(pts, minarr, cnt);
  k_fin<<<16, 256, 0, stream>>>(minarr, cnt, pix_i, sum_i, ticket, out);
}